// Round 1
// baseline (1293.585 us; speedup 1.0000x reference)
//
#include <hip/hip_runtime.h>
#include <hip/hip_bf16.h>
#include <math.h>

// ---------------- types / helpers ----------------
typedef float f32x4 __attribute__((ext_vector_type(4)));
typedef short s16x8 __attribute__((ext_vector_type(8)));

__device__ __forceinline__ float bf2f(unsigned short u){
  union { unsigned int i; float f; } v; v.i = ((unsigned int)u) << 16; return v.f;
}
__device__ __forceinline__ unsigned short f2bf(float f){
  union { float f; unsigned int i; } v; v.f = f;
  unsigned int r = v.i + 0x7FFFu + ((v.i >> 16) & 1u);
  return (unsigned short)(r >> 16);
}
__device__ __forceinline__ float dot4(f32x4 a, f32x4 b){
  return a.x*b.x + a.y*b.y + a.z*b.z + a.w*b.w;
}
__device__ __forceinline__ f32x4 mfma16(s16x8 a, s16x8 b, f32x4 c){
  return __builtin_amdgcn_mfma_f32_16x16x32_bf16(a, b, c, 0, 0, 0);
}

// ---------------- 1) time_feature ----------------
// tf[bt][d] = b_time[d] + sum_j (1 - tanh((s*W_sel[j]+b_sel[j])^2)) * W_time[d][j]
__global__ __launch_bounds__(256) void tf_kernel(
    const float* __restrict__ seq, const float* __restrict__ Wsel,
    const float* __restrict__ bsel, const float* __restrict__ Wtime,
    const float* __restrict__ btime, float* __restrict__ tf)
{
  const int bt = blockIdx.x, tid = threadIdx.x;
  __shared__ float w1[64];
  float s = seq[bt];
  if (tid < 64){ float h = s*Wsel[tid] + bsel[tid]; w1[tid] = 1.0f - tanhf(h*h); }
  __syncthreads();
  const float* wrow = Wtime + (size_t)tid*64;
  float acc = btime[tid];
  #pragma unroll 8
  for (int j = 0; j < 64; ++j) acc += w1[j]*wrow[j];
  tf[(size_t)bt*256 + tid] = acc;
}

// ---------------- 2) embed + gate (per modality) ----------------
template<int L, int N>
__global__ __launch_bounds__(256) void gate_kernel(
    const int* __restrict__ codes, const float* __restrict__ mask,
    const float* __restrict__ emb, const float* __restrict__ tf,
    const float* __restrict__ Wg, const float* __restrict__ bg,
    unsigned short* __restrict__ Xg, unsigned short* __restrict__ XgT, float scale)
{
  __shared__ float E[32*260];
  __shared__ float sc[64];
  __shared__ float tfs[256];
  __shared__ float gs[256];

  const int bt = blockIdx.x, b = bt/40, t = bt%40;
  const int tid = threadIdx.x, lane = tid & 63, wid = tid >> 6;

  tfs[tid] = tf[(size_t)bt*256 + tid];
  #pragma unroll
  for (int l = 0; l < L; ++l){
    int code = codes[bt*L + l];
    float m = mask[bt*L + l];
    E[l*260 + tid] = emb[(size_t)code*256 + tid] * m;
  }
  __syncthreads();

  constexpr int RPW = (L + 3)/4;
  #pragma unroll
  for (int rr = 0; rr < RPW; ++rr){
    int l = wid*RPW + rr;
    if (l < L){
      f32x4 e4 = *(const f32x4*)&E[l*260 + lane*4];
      f32x4 t4 = *(const f32x4*)&tfs[lane*4];
      float p = dot4(e4, t4);
      #pragma unroll
      for (int m = 1; m < 64; m <<= 1) p += __shfl_xor(p, m, 64);
      if (lane == 0) sc[l] = p * scale;
    }
  }
  __syncthreads();
  if (wid == 0){
    float p = (lane < L) ? __expf(sc[lane]) : 0.f;
    float ss = p;
    #pragma unroll
    for (int m = 1; m < 64; m <<= 1) ss += __shfl_xor(ss, m, 64);
    if (lane < L) sc[lane] = p / ss;
  }
  __syncthreads();

  float g = 0.f;
  #pragma unroll
  for (int l = 0; l < L; ++l) g += sc[l]*E[l*260 + tid];
  gs[tid] = g;
  __syncthreads();

  const float* wrow = Wg + (size_t)tid*256;
  float a2 = bg[tid];
  #pragma unroll
  for (int e = 0; e < 256; e += 4){
    f32x4 w4 = *(const f32x4*)&wrow[e];
    f32x4 g4 = *(const f32x4*)&gs[e];
    a2 += dot4(w4, g4);
  }
  float g2 = 1.f/(1.f + __expf(-a2));

  unsigned short tbuf[L];
  #pragma unroll
  for (int l = 0; l < L; ++l){
    unsigned short h = f2bf(g2 * E[l*260 + tid]);
    Xg[((size_t)b*N + t*L + l)*256 + tid] = h;
    tbuf[l] = h;
  }
  size_t tb = ((size_t)b*256 + tid)*N + (size_t)t*L;
  #pragma unroll
  for (int l = 0; l < L; l += 8){
    uint4 v;
    v.x = (unsigned)tbuf[l+0] | ((unsigned)tbuf[l+1] << 16);
    v.y = (unsigned)tbuf[l+2] | ((unsigned)tbuf[l+3] << 16);
    v.z = (unsigned)tbuf[l+4] | ((unsigned)tbuf[l+5] << 16);
    v.w = (unsigned)tbuf[l+6] | ((unsigned)tbuf[l+7] << 16);
    *(uint4*)&XgT[tb + l] = v;
  }
}

// ---------------- 3) visit self-attention (flash, bf16 MFMA) ----------------
// One block = 128 q-rows (4 waves x 32), loop over 32-row K/V tiles.
// No-max online softmax (logits provably tiny), O accumulated in f32, /= l at end.
template<int N>
__global__ __launch_bounds__(256, 1) void visit_kernel(
    const unsigned short* __restrict__ Xg, const unsigned short* __restrict__ XgT,
    unsigned short* __restrict__ Out, float scale)
{
  __shared__ unsigned short ks[32*256];   // K tile, row-major, XOR-swizzled
  __shared__ unsigned short vs[256*32];   // V tile transposed: [d][k], linear
  __shared__ unsigned short ps[4*32*40];  // per-wave P scratch [32][40]

  const int tid = threadIdx.x, lane = tid & 63, wid = tid >> 6;
  const int lc = lane & 15, lg = lane >> 4;
  const int b = blockIdx.y;
  const int q0 = blockIdx.x * 128;

  const unsigned short* Xb  = Xg  + (size_t)b * N * 256;
  const unsigned short* XTb = XgT + (size_t)b * 256 * N;

  // ---- load Q fragments: wave w owns rows q0 + w*32 .. +32 ----
  s16x8 qf[2][8];
  for (int cc = 0; cc < 4; ++cc){
    __syncthreads();
    #pragma unroll
    for (int i = 0; i < 4; ++i){
      int c = tid + i*256;
      int row = c >> 5, off = (c & 31) * 16;
      int gr = q0 + cc*32 + row; gr = gr < N ? gr : N-1;
      uint4 v = *(const uint4*)(Xb + (size_t)gr*256 + (off >> 1));
      *(uint4*)((char*)ks + row*512 + (off ^ ((row & 7) << 4))) = v;
    }
    __syncthreads();
    if (wid == cc){
      #pragma unroll
      for (int qg = 0; qg < 2; ++qg)
        #pragma unroll
        for (int kk = 0; kk < 8; ++kk){
          int row = qg*16 + lc;
          int off = kk*64 + lg*16;
          qf[qg][kk] = *(const s16x8*)((const char*)ks + row*512 + (off ^ ((row & 7) << 4)));
        }
    }
  }

  f32x4 o[2][16];
  #pragma unroll
  for (int qg = 0; qg < 2; ++qg)
    #pragma unroll
    for (int dc = 0; dc < 16; ++dc) o[qg][dc] = (f32x4){0.f,0.f,0.f,0.f};
  float lsum[2][4] = {{0.f,0.f,0.f,0.f},{0.f,0.f,0.f,0.f}};

  unsigned short* pw = ps + wid*32*40;

  for (int k0 = 0; k0 < N; k0 += 32){
    __syncthreads();
    #pragma unroll
    for (int i = 0; i < 4; ++i){       // stage K rows (swizzled)
      int c = tid + i*256;
      int row = c >> 5, off = (c & 31) * 16;
      uint4 v = *(const uint4*)(Xb + (size_t)(k0 + row)*256 + (off >> 1));
      *(uint4*)((char*)ks + row*512 + (off ^ ((row & 7) << 4))) = v;
    }
    #pragma unroll
    for (int i = 0; i < 4; ++i){       // stage Vt [d][k] from pre-transposed global
      int c = tid + i*256;
      int d = c >> 2, kslot = c & 3;
      uint4 v = *(const uint4*)(XTb + (size_t)d*N + k0 + kslot*8);
      *(uint4*)(vs + c*8) = v;
    }
    __syncthreads();

    // S = Q K^T (2 q-groups x 2 k-cols of 16x16)
    f32x4 s[2][2];
    #pragma unroll
    for (int qg = 0; qg < 2; ++qg)
      #pragma unroll
      for (int kc = 0; kc < 2; ++kc) s[qg][kc] = (f32x4){0.f,0.f,0.f,0.f};

    #pragma unroll
    for (int kk = 0; kk < 8; ++kk){
      #pragma unroll
      for (int kc = 0; kc < 2; ++kc){
        int row = kc*16 + lc;
        int off = kk*64 + lg*16;
        s16x8 kb = *(const s16x8*)((const char*)ks + row*512 + (off ^ ((row & 7) << 4)));
        s[0][kc] = mfma16(qf[0][kk], kb, s[0][kc]);
        s[1][kc] = mfma16(qf[1][kk], kb, s[1][kc]);
      }
    }

    // softmax numerator (no max needed: logits tiny), write P as bf16
    #pragma unroll
    for (int qg = 0; qg < 2; ++qg){
      #pragma unroll
      for (int r = 0; r < 4; ++r){
        float p0 = __expf(s[qg][0][r] * scale);
        float p1 = __expf(s[qg][1][r] * scale);
        int prow = qg*16 + lg*4 + r;
        pw[prow*40 + lc]      = f2bf(p0);
        pw[prow*40 + 16 + lc] = f2bf(p1);
        float rs = p0 + p1;
        rs += __shfl_xor(rs, 1, 64);
        rs += __shfl_xor(rs, 2, 64);
        rs += __shfl_xor(rs, 4, 64);
        rs += __shfl_xor(rs, 8, 64);
        lsum[qg][r] += rs;
      }
    }

    // O += P V
    s16x8 pa[2];
    #pragma unroll
    for (int qg = 0; qg < 2; ++qg)
      pa[qg] = *(const s16x8*)(pw + (qg*16 + lc)*40 + lg*8);
    #pragma unroll
    for (int dc = 0; dc < 16; ++dc){
      s16x8 vf = *(const s16x8*)(vs + (dc*16 + lc)*32 + lg*8);
      o[0][dc] = mfma16(pa[0], vf, o[0][dc]);
      o[1][dc] = mfma16(pa[1], vf, o[1][dc]);
    }
  }

  // epilogue: normalize and store bf16
  #pragma unroll
  for (int qg = 0; qg < 2; ++qg){
    f32x4 inv;
    inv.x = 1.f/lsum[qg][0]; inv.y = 1.f/lsum[qg][1];
    inv.z = 1.f/lsum[qg][2]; inv.w = 1.f/lsum[qg][3];
    #pragma unroll
    for (int r = 0; r < 4; ++r){
      int grow = q0 + wid*32 + qg*16 + lg*4 + r;
      if (grow < N){
        #pragma unroll
        for (int dc = 0; dc < 16; ++dc){
          Out[((size_t)b*N + grow)*256 + dc*16 + lc] = f2bf(o[qg][dc][r] * inv[r]);
        }
      }
    }
  }
}

// ---------------- 4) merge attention + med_att, fully fused per (b,t) ----------------
// out = sum_k u[k]*M[k] + bias + pos,  u = (w^T P),  w_j = sum_{i<24} P2[i][j],
// P2 = softmax(P Sr P^T rows<24), P = softmax(scale*Sr), Sr = M M^T
__global__ __launch_bounds__(256) void merge_kernel(
    const unsigned short* __restrict__ Amed,
    const unsigned short* __restrict__ Adiag,
    const unsigned short* __restrict__ Aproc,
    const float* __restrict__ tf,
    const float* __restrict__ bias,
    const int* __restrict__ ilen,
    float* __restrict__ out, float scale)
{
  __shared__ float M[73*260];
  __shared__ float Sr[73*76];
  __shared__ float P[73*76];
  __shared__ float W1[24*76];
  __shared__ float S2[24*76];
  __shared__ float wj[73];
  __shared__ float uk[73];

  const int bt = blockIdx.x, b = bt/40, t = bt%40;
  const int tid = threadIdx.x, lane = tid & 63, wid = tid >> 6;
  const int lc = lane & 15, lg = lane >> 4;

  #pragma unroll
  for (int r = 0; r < 24; ++r)
    M[r*260 + tid] = bf2f(Amed[((size_t)(b*960 + t*24 + r))*256 + tid]);
  #pragma unroll
  for (int r = 0; r < 32; ++r)
    M[(24+r)*260 + tid] = bf2f(Adiag[((size_t)(b*1280 + t*32 + r))*256 + tid]);
  #pragma unroll
  for (int r = 0; r < 16; ++r)
    M[(56+r)*260 + tid] = bf2f(Aproc[((size_t)(b*640 + t*16 + r))*256 + tid]);
  M[72*260 + tid] = tf[(size_t)bt*256 + tid];
  __syncthreads();

  // Sr = M M^T (pads j=73..75 zeroed)
  for (int i = wid; i < 73; i += 4){
    f32x4 mi[4];
    #pragma unroll
    for (int q = 0; q < 4; ++q) mi[q] = *(const f32x4*)&M[i*260 + lc*4 + 64*q];
    for (int jj = 0; jj < 19; ++jj){
      int j = jj*4 + lg;
      int jr = j < 73 ? j : 72;
      float acc = 0.f;
      #pragma unroll
      for (int q = 0; q < 4; ++q){
        f32x4 mj = *(const f32x4*)&M[jr*260 + lc*4 + 64*q];
        acc += dot4(mi[q], mj);
      }
      acc += __shfl_xor(acc, 1, 64);
      acc += __shfl_xor(acc, 2, 64);
      acc += __shfl_xor(acc, 4, 64);
      acc += __shfl_xor(acc, 8, 64);
      if (lc == 0) Sr[i*76 + j] = (j < 73) ? acc : 0.f;
    }
  }
  __syncthreads();

  // P = row-softmax(scale*Sr)
  for (int r = wid; r < 73; r += 4){
    float e0 = __expf(scale * Sr[r*76 + lane]);
    float e1 = (lane < 9) ? __expf(scale * Sr[r*76 + 64 + lane]) : 0.f;
    float ss = e0 + e1;
    #pragma unroll
    for (int m = 1; m < 64; m <<= 1) ss += __shfl_xor(ss, m, 64);
    float inv = 1.f/ss;
    P[r*76 + lane] = e0 * inv;
    if (lane < 12) P[r*76 + 64 + lane] = (lane < 9) ? e1*inv : 0.f;
  }
  __syncthreads();

  // W1 = (P Sr) rows 0..23
  for (int task = tid; task < 24*19; task += 256){
    int i = task/19, mq = task - (task/19)*19;
    f32x4 acc = (f32x4){0.f,0.f,0.f,0.f};
    for (int k = 0; k < 73; ++k){
      float p = P[i*76 + k];
      f32x4 s4 = *(const f32x4*)&Sr[k*76 + mq*4];
      acc.x += p*s4.x; acc.y += p*s4.y; acc.z += p*s4.z; acc.w += p*s4.w;
    }
    *(f32x4*)&W1[i*76 + mq*4] = acc;
  }
  __syncthreads();

  // S2 = W1 P^T (24 x 73)
  for (int e = tid; e < 24*73; e += 256){
    int i = e/73, j = e - (e/73)*73;
    float acc = 0.f;
    #pragma unroll
    for (int mq = 0; mq < 19; ++mq){
      f32x4 w4 = *(const f32x4*)&W1[i*76 + mq*4];
      f32x4 p4 = *(const f32x4*)&P[j*76 + mq*4];
      acc += dot4(w4, p4);
    }
    S2[i*76 + j] = acc;
  }
  __syncthreads();

  // P2 = row-softmax(S2) (no scale), in place, pads zeroed
  for (int r = wid; r < 24; r += 4){
    float e0 = __expf(S2[r*76 + lane]);
    float e1 = (lane < 9) ? __expf(S2[r*76 + 64 + lane]) : 0.f;
    float ss = e0 + e1;
    #pragma unroll
    for (int m = 1; m < 64; m <<= 1) ss += __shfl_xor(ss, m, 64);
    float inv = 1.f/ss;
    S2[r*76 + lane] = e0*inv;
    if (lane < 12) S2[r*76 + 64 + lane] = (lane < 9) ? e1*inv : 0.f;
  }
  __syncthreads();

  if (tid < 73){
    float a = 0.f;
    #pragma unroll
    for (int i = 0; i < 24; ++i) a += S2[i*76 + tid];
    wj[tid] = a;
  }
  __syncthreads();
  if (tid < 73){
    float a = 0.f;
    for (int j = 0; j < 73; ++j) a += wj[j]*P[j*76 + tid];
    uk[tid] = a;
  }
  __syncthreads();

  float acc = bias[tid];
  if (t < ilen[b]){
    float ex = (float)(2*(tid>>1)) * (1.0f/256.0f);
    float dv = powf(10000.f, ex);
    float ang = (float)t / dv;
    acc += (tid & 1) ? cosf(ang) : sinf(ang);
  }
  for (int k = 0; k < 73; ++k) acc += uk[k]*M[k*260 + tid];
  out[(size_t)bt*256 + tid] = acc;
}

// ---------------- launch ----------------
extern "C" void kernel_launch(void* const* d_in, const int* in_sizes, int n_in,
                              void* d_out, int out_size, void* d_ws, size_t ws_size,
                              hipStream_t stream)
{
  (void)in_sizes; (void)n_in; (void)out_size; (void)ws_size;

  const int*   med_codes = (const int*)  d_in[0];
  const int*   diag_codes= (const int*)  d_in[1];
  const int*   proc_codes= (const int*)  d_in[2];
  const float* med_mask  = (const float*)d_in[3];
  const float* diag_mask = (const float*)d_in[4];
  const float* proc_mask = (const float*)d_in[5];
  const float* seq_time  = (const float*)d_in[6];
  const int*   input_len = (const int*)  d_in[7];
  const float* emb_med   = (const float*)d_in[8];
  const float* emb_diag  = (const float*)d_in[9];
  const float* emb_proc  = (const float*)d_in[10];
  const float* bias_med  = (const float*)d_in[11];
  const float* W_sel     = (const float*)d_in[12];
  const float* b_sel     = (const float*)d_in[13];
  const float* W_time    = (const float*)d_in[14];
  const float* b_time    = (const float*)d_in[15];
  const float* Wg_med    = (const float*)d_in[16];
  const float* bg_med    = (const float*)d_in[17];
  const float* Wg_diag   = (const float*)d_in[18];
  const float* bg_diag   = (const float*)d_in[19];
  const float* Wg_proc   = (const float*)d_in[20];
  const float* bg_proc   = (const float*)d_in[21];

  char* ws = (char*)d_ws;
  size_t off = 0;
  float* tf             = (float*)(ws + off);          off += (size_t)1280*256*4;
  unsigned short* Amed  = (unsigned short*)(ws + off); off += (size_t)32*960*256*2;
  unsigned short* Adiag = (unsigned short*)(ws + off); off += (size_t)32*1280*256*2;
  unsigned short* Aproc = (unsigned short*)(ws + off); off += (size_t)32*640*256*2;
  unsigned short* Xg    = (unsigned short*)(ws + off); off += (size_t)32*1280*256*2;
  unsigned short* XgT   = (unsigned short*)(ws + off); off += (size_t)32*1280*256*2;

  const float scale = (float)(1.0 / sqrt(256.0 + 1e-7));

  tf_kernel<<<1280, 256, 0, stream>>>(seq_time, W_sel, b_sel, W_time, b_time, tf);

  gate_kernel<24,960><<<1280, 256, 0, stream>>>(med_codes, med_mask, emb_med, tf, Wg_med, bg_med, Xg, XgT, scale);
  visit_kernel<960><<<dim3(8,32), 256, 0, stream>>>(Xg, XgT, Amed, scale);

  gate_kernel<32,1280><<<1280, 256, 0, stream>>>(diag_codes, diag_mask, emb_diag, tf, Wg_diag, bg_diag, Xg, XgT, scale);
  visit_kernel<1280><<<dim3(10,32), 256, 0, stream>>>(Xg, XgT, Adiag, scale);

  gate_kernel<16,640><<<1280, 256, 0, stream>>>(proc_codes, proc_mask, emb_proc, tf, Wg_proc, bg_proc, Xg, XgT, scale);
  visit_kernel<640><<<dim3(5,32), 256, 0, stream>>>(Xg, XgT, Aproc, scale);

  merge_kernel<<<1280, 256, 0, stream>>>(Amed, Adiag, Aproc, tf, bias_med, input_len, (float*)d_out, scale);
}

// Round 2
// 573.567 us; speedup vs baseline: 2.2553x; 2.2553x over previous
//
#include <hip/hip_runtime.h>
#include <hip/hip_bf16.h>
#include <math.h>

// ---------------- types / helpers ----------------
typedef float f32x4 __attribute__((ext_vector_type(4)));
typedef short s16x8 __attribute__((ext_vector_type(8)));

__device__ __forceinline__ float bf2f(unsigned short u){
  union { unsigned int i; float f; } v; v.i = ((unsigned int)u) << 16; return v.f;
}
__device__ __forceinline__ unsigned short f2bf(float f){
  union { float f; unsigned int i; } v; v.f = f;
  unsigned int r = v.i + 0x7FFFu + ((v.i >> 16) & 1u);
  return (unsigned short)(r >> 16);
}
__device__ __forceinline__ float dot4(f32x4 a, f32x4 b){
  return a.x*b.x + a.y*b.y + a.z*b.z + a.w*b.w;
}
__device__ __forceinline__ f32x4 mfma16(s16x8 a, s16x8 b, f32x4 c){
  return __builtin_amdgcn_mfma_f32_16x16x32_bf16(a, b, c, 0, 0, 0);
}
// async global->LDS, 16B per lane; dst must be wave-uniform base (HW adds lane*16)
__device__ __forceinline__ void gld16(const unsigned short* src, unsigned short* dst){
  __builtin_amdgcn_global_load_lds(
      (const __attribute__((address_space(1))) unsigned int*)src,
      (__attribute__((address_space(3))) unsigned int*)dst, 16, 0, 0);
}

// ---------------- 1) time_feature ----------------
__global__ __launch_bounds__(256) void tf_kernel(
    const float* __restrict__ seq, const float* __restrict__ Wsel,
    const float* __restrict__ bsel, const float* __restrict__ Wtime,
    const float* __restrict__ btime, float* __restrict__ tf)
{
  const int bt = blockIdx.x, tid = threadIdx.x;
  __shared__ float w1[64];
  float s = seq[bt];
  if (tid < 64){ float h = s*Wsel[tid] + bsel[tid]; w1[tid] = 1.0f - tanhf(h*h); }
  __syncthreads();
  const float* wrow = Wtime + (size_t)tid*64;
  float acc = btime[tid];
  #pragma unroll 8
  for (int j = 0; j < 64; ++j) acc += w1[j]*wrow[j];
  tf[(size_t)bt*256 + tid] = acc;
}

// ---------------- 2) embed + gate ----------------
struct GateLds {
  float E[32*260];
  float sc[64];
  float tfs[256];
  float gs[256];
};

template<int L, int N>
__device__ __forceinline__ void gate_body(GateLds& S,
    const int* __restrict__ codes, const float* __restrict__ mask,
    const float* __restrict__ emb, const float* __restrict__ tf,
    const float* __restrict__ Wg, const float* __restrict__ bg,
    unsigned short* __restrict__ Xg, unsigned short* __restrict__ XgT,
    float scale, int bt)
{
  const int b = bt/40, t = bt - (bt/40)*40;
  const int tid = threadIdx.x, lane = tid & 63, wid = tid >> 6;

  S.tfs[tid] = tf[(size_t)bt*256 + tid];
  #pragma unroll
  for (int l = 0; l < L; ++l){
    int code = codes[bt*L + l];
    float m = mask[bt*L + l];
    S.E[l*260 + tid] = emb[(size_t)code*256 + tid] * m;
  }
  __syncthreads();

  constexpr int RPW = (L + 3)/4;
  #pragma unroll
  for (int rr = 0; rr < RPW; ++rr){
    int l = wid*RPW + rr;
    if (l < L){
      f32x4 e4 = *(const f32x4*)&S.E[l*260 + lane*4];
      f32x4 t4 = *(const f32x4*)&S.tfs[lane*4];
      float p = dot4(e4, t4);
      #pragma unroll
      for (int m = 1; m < 64; m <<= 1) p += __shfl_xor(p, m, 64);
      if (lane == 0) S.sc[l] = p * scale;
    }
  }
  __syncthreads();
  if (wid == 0){
    float p = (lane < L) ? __expf(S.sc[lane]) : 0.f;
    float ss = p;
    #pragma unroll
    for (int m = 1; m < 64; m <<= 1) ss += __shfl_xor(ss, m, 64);
    if (lane < L) S.sc[lane] = p / ss;
  }
  __syncthreads();

  float g = 0.f;
  #pragma unroll
  for (int l = 0; l < L; ++l) g += S.sc[l]*S.E[l*260 + tid];
  S.gs[tid] = g;
  __syncthreads();

  const float* wrow = Wg + (size_t)tid*256;
  float a2 = bg[tid];
  #pragma unroll
  for (int e = 0; e < 256; e += 4){
    f32x4 w4 = *(const f32x4*)&wrow[e];
    f32x4 g4 = *(const f32x4*)&S.gs[e];
    a2 += dot4(w4, g4);
  }
  float g2 = 1.f/(1.f + __expf(-a2));

  unsigned short tbuf[L];
  #pragma unroll
  for (int l = 0; l < L; ++l){
    unsigned short h = f2bf(g2 * S.E[l*260 + tid]);
    Xg[((size_t)b*N + t*L + l)*256 + tid] = h;
    tbuf[l] = h;
  }
  size_t tb = ((size_t)b*256 + tid)*N + (size_t)t*L;
  #pragma unroll
  for (int l = 0; l < L; l += 8){
    uint4 v;
    v.x = (unsigned)tbuf[l+0] | ((unsigned)tbuf[l+1] << 16);
    v.y = (unsigned)tbuf[l+2] | ((unsigned)tbuf[l+3] << 16);
    v.z = (unsigned)tbuf[l+4] | ((unsigned)tbuf[l+5] << 16);
    v.w = (unsigned)tbuf[l+6] | ((unsigned)tbuf[l+7] << 16);
    *(uint4*)&XgT[tb + l] = v;
  }
}

template<int L, int N>
__global__ __launch_bounds__(256) void gate_kernel(
    const int* codes, const float* mask, const float* emb, const float* tf,
    const float* Wg, const float* bg, unsigned short* Xg, unsigned short* XgT, float scale)
{
  __shared__ GateLds S;
  gate_body<L,N>(S, codes, mask, emb, tf, Wg, bg, Xg, XgT, scale, blockIdx.x);
}

__global__ __launch_bounds__(256) void gate_fused(
    const int* mc, const int* dc, const int* pc,
    const float* mm, const float* dm, const float* pm,
    const float* em, const float* ed, const float* ep,
    const float* tf,
    const float* Wgm, const float* bgm, const float* Wgd, const float* bgd,
    const float* Wgp, const float* bgp,
    unsigned short* Xm, unsigned short* XTm,
    unsigned short* Xd, unsigned short* XTd,
    unsigned short* Xp, unsigned short* XTp, float scale)
{
  __shared__ GateLds S;
  int bid = blockIdx.x;
  if (bid < 1280)      gate_body<24,960 >(S, mc, mm, em, tf, Wgm, bgm, Xm, XTm, scale, bid);
  else if (bid < 2560) gate_body<32,1280>(S, dc, dm, ed, tf, Wgd, bgd, Xd, XTd, scale, bid-1280);
  else                 gate_body<16,640 >(S, pc, pm, ep, tf, Wgp, bgp, Xp, XTp, scale, bid-2560);
}

// ---------------- 3) visit self-attention (flash, bf16 MFMA) ----------------
struct VisitLds {
  unsigned short ks[32*256];   // K tile, row-major, XOR-swizzled (linear dest, pre-swz src)
  unsigned short vs[256*32];   // V tile transposed [d][k], linear
  unsigned short ps[4*32*40];  // per-wave P scratch [32][40]
};

template<int N>
__device__ __forceinline__ void visit_body(VisitLds& S,
    const unsigned short* __restrict__ Xb, const unsigned short* __restrict__ XTb,
    unsigned short* __restrict__ Outb, float scale, int q0)
{
  const int tid = threadIdx.x, lane = tid & 63, wid = tid >> 6;
  const int lc = lane & 15, lg = lane >> 4;

  // ---- Q fragments via async staging through ks ----
  s16x8 qf[2][8];
  for (int cc = 0; cc < 4; ++cc){
    __syncthreads();
    #pragma unroll
    for (int i = 0; i < 4; ++i){
      int c = tid + i*256;
      int row = c >> 5, off = (c & 31) * 16;
      int gr = q0 + cc*32 + row; gr = gr < N ? gr : N-1;
      gld16(Xb + (size_t)gr*256 + ((off ^ ((row & 7) << 4)) >> 1),
            S.ks + (size_t)(wid*64 + i*256)*8);
    }
    __syncthreads();
    if (wid == cc){
      #pragma unroll
      for (int qg = 0; qg < 2; ++qg)
        #pragma unroll
        for (int kk = 0; kk < 8; ++kk){
          int row = qg*16 + lc;
          int off = kk*64 + lg*16;
          qf[qg][kk] = *(const s16x8*)((const char*)S.ks + row*512 + (off ^ ((row & 7) << 4)));
        }
    }
  }

  f32x4 o[2][16];
  #pragma unroll
  for (int qg = 0; qg < 2; ++qg)
    #pragma unroll
    for (int dc = 0; dc < 16; ++dc) o[qg][dc] = (f32x4){0.f,0.f,0.f,0.f};
  float lsum[2][4] = {{0.f,0.f,0.f,0.f},{0.f,0.f,0.f,0.f}};

  unsigned short* pw = S.ps + wid*32*40;

  for (int k0 = 0; k0 < N; k0 += 32){
    __syncthreads();
    #pragma unroll
    for (int i = 0; i < 4; ++i){
      int c = tid + i*256;
      int row = c >> 5, off = (c & 31) * 16;
      gld16(Xb + (size_t)(k0 + row)*256 + ((off ^ ((row & 7) << 4)) >> 1),
            S.ks + (size_t)(wid*64 + i*256)*8);
      int d = c >> 2, kslot = c & 3;
      gld16(XTb + (size_t)d*N + k0 + kslot*8,
            S.vs + (size_t)(wid*64 + i*256)*8);
    }
    __syncthreads();

    f32x4 s[2][2];
    #pragma unroll
    for (int qg = 0; qg < 2; ++qg)
      #pragma unroll
      for (int kc = 0; kc < 2; ++kc) s[qg][kc] = (f32x4){0.f,0.f,0.f,0.f};

    #pragma unroll
    for (int kk = 0; kk < 8; ++kk){
      #pragma unroll
      for (int kc = 0; kc < 2; ++kc){
        int row = kc*16 + lc;
        int off = kk*64 + lg*16;
        s16x8 kb = *(const s16x8*)((const char*)S.ks + row*512 + (off ^ ((row & 7) << 4)));
        s[0][kc] = mfma16(qf[0][kk], kb, s[0][kc]);
        s[1][kc] = mfma16(qf[1][kk], kb, s[1][kc]);
      }
    }

    #pragma unroll
    for (int qg = 0; qg < 2; ++qg){
      #pragma unroll
      for (int r = 0; r < 4; ++r){
        float p0 = __expf(s[qg][0][r] * scale);
        float p1 = __expf(s[qg][1][r] * scale);
        int prow = qg*16 + lg*4 + r;
        pw[prow*40 + lc]      = f2bf(p0);
        pw[prow*40 + 16 + lc] = f2bf(p1);
        float rs = p0 + p1;
        rs += __shfl_xor(rs, 1, 64);
        rs += __shfl_xor(rs, 2, 64);
        rs += __shfl_xor(rs, 4, 64);
        rs += __shfl_xor(rs, 8, 64);
        lsum[qg][r] += rs;
      }
    }

    s16x8 pa[2];
    #pragma unroll
    for (int qg = 0; qg < 2; ++qg)
      pa[qg] = *(const s16x8*)(pw + (qg*16 + lc)*40 + lg*8);
    #pragma unroll
    for (int dc = 0; dc < 16; ++dc){
      s16x8 vf = *(const s16x8*)(S.vs + (dc*16 + lc)*32 + lg*8);
      o[0][dc] = mfma16(pa[0], vf, o[0][dc]);
      o[1][dc] = mfma16(pa[1], vf, o[1][dc]);
    }
  }

  #pragma unroll
  for (int qg = 0; qg < 2; ++qg){
    f32x4 inv;
    inv.x = 1.f/lsum[qg][0]; inv.y = 1.f/lsum[qg][1];
    inv.z = 1.f/lsum[qg][2]; inv.w = 1.f/lsum[qg][3];
    #pragma unroll
    for (int r = 0; r < 4; ++r){
      int grow = q0 + wid*32 + qg*16 + lg*4 + r;
      if (grow < N){
        #pragma unroll
        for (int dc = 0; dc < 16; ++dc){
          Outb[(size_t)grow*256 + dc*16 + lc] = f2bf(o[qg][dc][r] * inv[r]);
        }
      }
    }
  }
}

template<int N>
__global__ __launch_bounds__(256) void visit_kernel(
    const unsigned short* Xg, const unsigned short* XgT, unsigned short* Out, float scale)
{
  __shared__ VisitLds S;
  const int b = blockIdx.y;
  visit_body<N>(S, Xg + (size_t)b*N*256, XgT + (size_t)b*256*N,
                Out + (size_t)b*N*256, scale, blockIdx.x*128);
}

__global__ __launch_bounds__(256) void visit_fused(
    const unsigned short* Xm, const unsigned short* XTm, unsigned short* Am,
    const unsigned short* Xd, const unsigned short* XTd, unsigned short* Ad,
    const unsigned short* Xp, const unsigned short* XTp, unsigned short* Ap, float scale)
{
  __shared__ VisitLds S;
  int bid = blockIdx.x;
  if (bid < 256){
    int b = bid >> 3, q0 = (bid & 7)*128;
    visit_body<960>(S, Xm + (size_t)b*960*256, XTm + (size_t)b*256*960,
                    Am + (size_t)b*960*256, scale, q0);
  } else if (bid < 576){
    int r = bid - 256, b = r/10, q0 = (r - (r/10)*10)*128;
    visit_body<1280>(S, Xd + (size_t)b*1280*256, XTd + (size_t)b*256*1280,
                     Ad + (size_t)b*1280*256, scale, q0);
  } else {
    int r = bid - 576, b = r/5, q0 = (r - (r/5)*5)*128;
    visit_body<640>(S, Xp + (size_t)b*640*256, XTp + (size_t)b*256*640,
                    Ap + (size_t)b*640*256, scale, q0);
  }
}

// ---------------- 4) merge attention + med_att, fused per (b,t), MFMA Sr ----------------
__global__ __launch_bounds__(512) void merge_kernel(
    const unsigned short* __restrict__ Amed,
    const unsigned short* __restrict__ Adiag,
    const unsigned short* __restrict__ Aproc,
    const float* __restrict__ tf,
    const float* __restrict__ bias,
    const int* __restrict__ ilen,
    float* __restrict__ out, float scale)
{
  __shared__ unsigned short Mb[80*256];  // bf16, 512B rows, XOR-swizzled
  __shared__ float Sr[80*84];
  __shared__ float P[80*84];
  __shared__ float W1[24*76];
  __shared__ float S2[24*76];
  __shared__ float wj[73];
  __shared__ float uk[73];

  const int bt = blockIdx.x, b = bt/40, t = bt - (bt/40)*40;
  const int tid = threadIdx.x, lane = tid & 63, wid = tid >> 6;
  const int lc = lane & 15, lg = lane >> 4;

  // ---- stage M (rows 0..71 bf16, row 72 = tf, rows 73..79 zero) ----
  for (int c = tid; c < 72*32; c += 512){
    int row = c >> 5, ch = c & 31;
    const unsigned short* src;
    if (row < 24)      src = Amed  + ((size_t)b*960  + t*24 + row)*256      + ch*8;
    else if (row < 56) src = Adiag + ((size_t)b*1280 + t*32 + (row-24))*256 + ch*8;
    else               src = Aproc + ((size_t)b*640  + t*16 + (row-56))*256 + ch*8;
    uint4 v = *(const uint4*)src;
    *(uint4*)((char*)Mb + row*512 + ((ch*16) ^ ((row & 7) << 4))) = v;
  }
  if (tid < 256) Mb[72*256 + tid] = f2bf(tf[(size_t)bt*256 + tid]);
  for (int c = tid; c < 7*32; c += 512){
    int row = 73 + (c >> 5), ch = c & 31;
    *(uint4*)((char*)Mb + row*512 + ch*16) = (uint4){0,0,0,0};
  }
  __syncthreads();

  // ---- Sr = M M^T via MFMA: 5x5 tiles of 16x16, K=256 ----
  for (int tt = wid; tt < 25; tt += 8){
    int ti = tt/5, tj = tt - (tt/5)*5;
    f32x4 s = (f32x4){0.f,0.f,0.f,0.f};
    #pragma unroll
    for (int kk = 0; kk < 8; ++kk){
      int ra = ti*16 + lc, rb = tj*16 + lc;
      int off = kk*64 + lg*16;
      s16x8 a  = *(const s16x8*)((const char*)Mb + ra*512 + (off ^ ((ra & 7) << 4)));
      s16x8 bb = *(const s16x8*)((const char*)Mb + rb*512 + (off ^ ((rb & 7) << 4)));
      s = mfma16(a, bb, s);
    }
    #pragma unroll
    for (int r = 0; r < 4; ++r)
      Sr[(ti*16 + lg*4 + r)*84 + tj*16 + lc] = s[r];
  }
  __syncthreads();

  // ---- P = row-softmax(scale*Sr), cols<73; pad cols 73..75 zeroed ----
  for (int r = wid; r < 73; r += 8){
    float e0 = __expf(scale * Sr[r*84 + lane]);
    float e1 = (lane < 9) ? __expf(scale * Sr[r*84 + 64 + lane]) : 0.f;
    float ss = e0 + e1;
    #pragma unroll
    for (int m = 1; m < 64; m <<= 1) ss += __shfl_xor(ss, m, 64);
    float inv = 1.f/ss;
    P[r*84 + lane] = e0 * inv;
    if (lane < 12) P[r*84 + 64 + lane] = (lane < 9) ? e1*inv : 0.f;
  }
  __syncthreads();

  // ---- W1 = (P Sr), rows 0..23, cols padded to 76 ----
  if (tid < 456){
    int i = tid/19, mq = tid - (tid/19)*19;
    f32x4 acc = (f32x4){0.f,0.f,0.f,0.f};
    for (int k = 0; k < 73; ++k){
      float p = P[i*84 + k];
      f32x4 s4 = *(const f32x4*)&Sr[k*84 + mq*4];
      acc.x += p*s4.x; acc.y += p*s4.y; acc.z += p*s4.z; acc.w += p*s4.w;
    }
    *(f32x4*)&W1[i*76 + mq*4] = acc;
  }
  __syncthreads();

  // ---- S2 = W1 P^T (24 x 73) ----
  for (int e = tid; e < 24*73; e += 512){
    int i = e/73, j = e - (e/73)*73;
    float acc = 0.f;
    #pragma unroll
    for (int mq = 0; mq < 19; ++mq)
      acc += dot4(*(const f32x4*)&W1[i*76 + mq*4], *(const f32x4*)&P[j*84 + mq*4]);
    S2[i*76 + j] = acc;
  }
  __syncthreads();

  // ---- P2 = row-softmax(S2) in place ----
  for (int r = wid; r < 24; r += 8){
    float e0 = __expf(S2[r*76 + lane]);
    float e1 = (lane < 9) ? __expf(S2[r*76 + 64 + lane]) : 0.f;
    float ss = e0 + e1;
    #pragma unroll
    for (int m = 1; m < 64; m <<= 1) ss += __shfl_xor(ss, m, 64);
    float inv = 1.f/ss;
    S2[r*76 + lane] = e0*inv;
    if (lane < 12) S2[r*76 + 64 + lane] = (lane < 9) ? e1*inv : 0.f;
  }
  __syncthreads();

  if (tid < 73){
    float a = 0.f;
    #pragma unroll
    for (int i = 0; i < 24; ++i) a += S2[i*76 + tid];
    wj[tid] = a;
  }
  __syncthreads();
  if (tid < 73){
    float a = 0.f;
    for (int j = 0; j < 73; ++j) a += wj[j]*P[j*84 + tid];
    uk[tid] = a;
  }
  __syncthreads();

  if (tid < 256){
    float acc = bias[tid];
    if (t < ilen[b]){
      float ex = (float)(2*(tid>>1)) * (1.0f/256.0f);
      float dv = powf(10000.f, ex);
      float ang = (float)t / dv;
      acc += (tid & 1) ? cosf(ang) : sinf(ang);
    }
    for (int k = 0; k < 73; ++k){
      unsigned short m = *(const unsigned short*)((const char*)Mb + k*512 + ((tid*2) ^ ((k & 7) << 4)));
      acc += uk[k] * bf2f(m);
    }
    out[(size_t)bt*256 + tid] = acc;
  }
}

// ---------------- launch ----------------
extern "C" void kernel_launch(void* const* d_in, const int* in_sizes, int n_in,
                              void* d_out, int out_size, void* d_ws, size_t ws_size,
                              hipStream_t stream)
{
  (void)in_sizes; (void)n_in; (void)out_size;

  const int*   med_codes = (const int*)  d_in[0];
  const int*   diag_codes= (const int*)  d_in[1];
  const int*   proc_codes= (const int*)  d_in[2];
  const float* med_mask  = (const float*)d_in[3];
  const float* diag_mask = (const float*)d_in[4];
  const float* proc_mask = (const float*)d_in[5];
  const float* seq_time  = (const float*)d_in[6];
  const int*   input_len = (const int*)  d_in[7];
  const float* emb_med   = (const float*)d_in[8];
  const float* emb_diag  = (const float*)d_in[9];
  const float* emb_proc  = (const float*)d_in[10];
  const float* bias_med  = (const float*)d_in[11];
  const float* W_sel     = (const float*)d_in[12];
  const float* b_sel     = (const float*)d_in[13];
  const float* W_time    = (const float*)d_in[14];
  const float* b_time    = (const float*)d_in[15];
  const float* Wg_med    = (const float*)d_in[16];
  const float* bg_med    = (const float*)d_in[17];
  const float* Wg_diag   = (const float*)d_in[18];
  const float* bg_diag   = (const float*)d_in[19];
  const float* Wg_proc   = (const float*)d_in[20];
  const float* bg_proc   = (const float*)d_in[21];

  const float scale = (float)(1.0 / sqrt(256.0 + 1e-7));

  char* ws = (char*)d_ws;
  const size_t sz_tf = (size_t)1280*256*4;
  const size_t szA_m = (size_t)32*960*256*2;
  const size_t szA_d = (size_t)32*1280*256*2;
  const size_t szA_p = (size_t)32*640*256*2;

  size_t off = 0;
  float* tf            = (float*)(ws + off);          off += sz_tf;
  unsigned short* Am   = (unsigned short*)(ws + off); off += szA_m;
  unsigned short* Ad   = (unsigned short*)(ws + off); off += szA_d;
  unsigned short* Ap   = (unsigned short*)(ws + off); off += szA_p;

  const size_t fused_need = off + 2*(szA_m + szA_d + szA_p);
  tf_kernel<<<1280, 256, 0, stream>>>(seq_time, W_sel, b_sel, W_time, b_time, tf);

  if (ws_size >= fused_need){
    unsigned short* Xm  = (unsigned short*)(ws + off); off += szA_m;
    unsigned short* XTm = (unsigned short*)(ws + off); off += szA_m;
    unsigned short* Xd  = (unsigned short*)(ws + off); off += szA_d;
    unsigned short* XTd = (unsigned short*)(ws + off); off += szA_d;
    unsigned short* Xp  = (unsigned short*)(ws + off); off += szA_p;
    unsigned short* XTp = (unsigned short*)(ws + off); off += szA_p;

    gate_fused<<<3840, 256, 0, stream>>>(
        med_codes, diag_codes, proc_codes, med_mask, diag_mask, proc_mask,
        emb_med, emb_diag, emb_proc, tf,
        Wg_med, bg_med, Wg_diag, bg_diag, Wg_proc, bg_proc,
        Xm, XTm, Xd, XTd, Xp, XTp, scale);

    visit_fused<<<736, 256, 0, stream>>>(Xm, XTm, Am, Xd, XTd, Ad, Xp, XTp, Ap, scale);
  } else {
    unsigned short* Xg  = (unsigned short*)(ws + off);
    unsigned short* XgT = (unsigned short*)(ws + off + szA_d);

    gate_kernel<24,960><<<1280, 256, 0, stream>>>(med_codes, med_mask, emb_med, tf, Wg_med, bg_med, Xg, XgT, scale);
    visit_kernel<960><<<dim3(8,32), 256, 0, stream>>>(Xg, XgT, Am, scale);

    gate_kernel<32,1280><<<1280, 256, 0, stream>>>(diag_codes, diag_mask, emb_diag, tf, Wg_diag, bg_diag, Xg, XgT, scale);
    visit_kernel<1280><<<dim3(10,32), 256, 0, stream>>>(Xg, XgT, Ad, scale);

    gate_kernel<16,640><<<1280, 256, 0, stream>>>(proc_codes, proc_mask, emb_proc, tf, Wg_proc, bg_proc, Xg, XgT, scale);
    visit_kernel<640><<<dim3(5,32), 256, 0, stream>>>(Xg, XgT, Ap, scale);
  }

  merge_kernel<<<1280, 512, 0, stream>>>(Am, Ad, Ap, tf, bias_med, input_len, (float*)d_out, scale);
}

// Round 3
// 442.617 us; speedup vs baseline: 2.9226x; 1.2959x over previous
//
#include <hip/hip_runtime.h>
#include <hip/hip_bf16.h>
#include <math.h>

// ---------------- types / helpers ----------------
typedef float f32x4 __attribute__((ext_vector_type(4)));
typedef short s16x8 __attribute__((ext_vector_type(8)));
typedef unsigned short us;

__device__ __forceinline__ float bf2f(us u){
  union { unsigned int i; float f; } v; v.i = ((unsigned int)u) << 16; return v.f;
}
__device__ __forceinline__ us f2bf(float f){
  union { float f; unsigned int i; } v; v.f = f;
  unsigned int r = v.i + 0x7FFFu + ((v.i >> 16) & 1u);
  return (us)(r >> 16);
}
__device__ __forceinline__ float dot4(f32x4 a, f32x4 b){
  return a.x*b.x + a.y*b.y + a.z*b.z + a.w*b.w;
}
__device__ __forceinline__ f32x4 mfma16(s16x8 a, s16x8 b, f32x4 c){
  return __builtin_amdgcn_mfma_f32_16x16x32_bf16(a, b, c, 0, 0, 0);
}
// async global->LDS, 16B per lane; dst must be wave-uniform base (HW adds lane*16)
__device__ __forceinline__ void gld16(const us* src, us* dst){
  __builtin_amdgcn_global_load_lds(
      (const __attribute__((address_space(1))) unsigned int*)src,
      (__attribute__((address_space(3))) unsigned int*)dst, 16, 0, 0);
}

// ---------------- 1) time_feature ----------------
__global__ __launch_bounds__(256) void tf_kernel(
    const float* __restrict__ seq, const float* __restrict__ Wsel,
    const float* __restrict__ bsel, const float* __restrict__ Wtime,
    const float* __restrict__ btime, float* __restrict__ tf)
{
  const int bt = blockIdx.x, tid = threadIdx.x;
  __shared__ float w1[64];
  float s = seq[bt];
  if (tid < 64){ float h = s*Wsel[tid] + bsel[tid]; w1[tid] = 1.0f - tanhf(h*h); }
  __syncthreads();
  const float* wrow = Wtime + (size_t)tid*64;
  float acc = btime[tid];
  #pragma unroll 8
  for (int j = 0; j < 64; ++j) acc += w1[j]*wrow[j];
  tf[(size_t)bt*256 + tid] = acc;
}

// ---------------- 2) embed + gate ----------------
struct GateLds {
  float E[32*260];
  float sc[64];
  float tfs[256];
  float gs[256];
};

template<int L, int N>
__device__ __forceinline__ void gate_body(GateLds& S,
    const int* __restrict__ codes, const float* __restrict__ mask,
    const float* __restrict__ emb, const float* __restrict__ tf,
    const float* __restrict__ Wg, const float* __restrict__ bg,
    us* __restrict__ Xg, us* __restrict__ XgT, float scale, int bt)
{
  const int b = bt/40, t = bt - (bt/40)*40;
  const int tid = threadIdx.x, lane = tid & 63, wid = tid >> 6;

  S.tfs[tid] = tf[(size_t)bt*256 + tid];
  #pragma unroll
  for (int l = 0; l < L; ++l){
    int code = codes[bt*L + l];
    float m = mask[bt*L + l];
    S.E[l*260 + tid] = emb[(size_t)code*256 + tid] * m;
  }
  __syncthreads();

  constexpr int RPW = (L + 3)/4;
  #pragma unroll
  for (int rr = 0; rr < RPW; ++rr){
    int l = wid*RPW + rr;
    if (l < L){
      f32x4 e4 = *(const f32x4*)&S.E[l*260 + lane*4];
      f32x4 t4 = *(const f32x4*)&S.tfs[lane*4];
      float p = dot4(e4, t4);
      #pragma unroll
      for (int m = 1; m < 64; m <<= 1) p += __shfl_xor(p, m, 64);
      if (lane == 0) S.sc[l] = p * scale;
    }
  }
  __syncthreads();
  if (wid == 0){
    float p = (lane < L) ? __expf(S.sc[lane]) : 0.f;
    float ss = p;
    #pragma unroll
    for (int m = 1; m < 64; m <<= 1) ss += __shfl_xor(ss, m, 64);
    if (lane < L) S.sc[lane] = p / ss;
  }
  __syncthreads();

  float g = 0.f;
  #pragma unroll
  for (int l = 0; l < L; ++l) g += S.sc[l]*S.E[l*260 + tid];
  S.gs[tid] = g;
  __syncthreads();

  const float* wrow = Wg + (size_t)tid*256;
  float a2 = bg[tid];
  #pragma unroll
  for (int e = 0; e < 256; e += 4){
    f32x4 w4 = *(const f32x4*)&wrow[e];
    f32x4 g4 = *(const f32x4*)&S.gs[e];
    a2 += dot4(w4, g4);
  }
  float g2 = 1.f/(1.f + __expf(-a2));

  us tbuf[L];
  #pragma unroll
  for (int l = 0; l < L; ++l){
    us h = f2bf(g2 * S.E[l*260 + tid]);
    Xg[((size_t)b*N + t*L + l)*256 + tid] = h;
    tbuf[l] = h;
  }
  size_t tb = ((size_t)b*256 + tid)*N + (size_t)t*L;
  #pragma unroll
  for (int l = 0; l < L; l += 8){
    uint4 v;
    v.x = (unsigned)tbuf[l+0] | ((unsigned)tbuf[l+1] << 16);
    v.y = (unsigned)tbuf[l+2] | ((unsigned)tbuf[l+3] << 16);
    v.z = (unsigned)tbuf[l+4] | ((unsigned)tbuf[l+5] << 16);
    v.w = (unsigned)tbuf[l+6] | ((unsigned)tbuf[l+7] << 16);
    *(uint4*)&XgT[tb + l] = v;
  }
}

template<int L, int N>
__global__ __launch_bounds__(256) void gate_kernel(
    const int* codes, const float* mask, const float* emb, const float* tf,
    const float* Wg, const float* bg, us* Xg, us* XgT, float scale)
{
  __shared__ GateLds S;
  gate_body<L,N>(S, codes, mask, emb, tf, Wg, bg, Xg, XgT, scale, blockIdx.x);
}

__global__ __launch_bounds__(256) void gate_fused(
    const int* mc, const int* dc, const int* pc,
    const float* mm, const float* dm, const float* pm,
    const float* em, const float* ed, const float* ep,
    const float* tf,
    const float* Wgm, const float* bgm, const float* Wgd, const float* bgd,
    const float* Wgp, const float* bgp,
    us* Xm, us* XTm, us* Xd, us* XTd, us* Xp, us* XTp, float scale)
{
  __shared__ GateLds S;
  int bid = blockIdx.x;
  if (bid < 1280)      gate_body<24,960 >(S, mc, mm, em, tf, Wgm, bgm, Xm, XTm, scale, bid);
  else if (bid < 2560) gate_body<32,1280>(S, dc, dm, ed, tf, Wgd, bgd, Xd, XTd, scale, bid-1280);
  else                 gate_body<16,640 >(S, pc, pm, ep, tf, Wgp, bgp, Xp, XTp, scale, bid-2560);
}

// ---------------- 3) visit self-attention (flash, bf16 MFMA, 2-phase dbuf) ----------------
// LDS map (shorts): KS0 [0,8192) KS1 [8192,16384) VS0 [16384,25088) VS1 [25088,33792)
// VSx rows 0..255 = V^T [d][k] tile (linear); rows 256..271: row256=ones, rest 0.
// Q staged once through [0, 32768) (64KB) before the loop.
struct VisitLds {
  us buf[33792];
  us ps[4*32*40];   // per-wave P scratch [32][40]
};

__device__ __forceinline__ void stage_tile(VisitLds& S, int cur,
    const us* __restrict__ Xb, const us* __restrict__ XTb, int k0, int N_, int tid)
{
  const int wid = tid >> 6;
  us* KS = S.buf + cur*8192;
  us* VS = S.buf + 16384 + cur*8704;
  #pragma unroll
  for (int i = 0; i < 4; ++i){
    int c = tid + i*256;
    int row = c >> 5, ch = c & 31;
    gld16(Xb + (size_t)(k0 + row)*256 + (((ch*16) ^ ((row & 7) << 4)) >> 1),
          KS + (i*256 + wid*64)*8);
    int d = c >> 2, kslot = c & 3;
    gld16(XTb + (size_t)d*N_ + k0 + kslot*8,
          VS + (i*256 + wid*64)*8);
  }
}

template<int N>
__device__ __forceinline__ void visit_body(VisitLds& S,
    const us* __restrict__ Xb, const us* __restrict__ XTb,
    us* __restrict__ Outb, float scale, int q0)
{
  const int tid = threadIdx.x, lane = tid & 63, wid = tid >> 6;
  const int lc = lane & 15, lg = lane >> 4;

  // ---- stage all 128 Q rows (64KB) in one shot ----
  #pragma unroll
  for (int i = 0; i < 16; ++i){
    int c = tid + i*256, row = c >> 5, ch = c & 31;
    int gr = q0 + row; gr = gr < N ? gr : N-1;
    gld16(Xb + (size_t)gr*256 + (((ch*16) ^ ((row & 7) << 4)) >> 1),
          S.buf + (i*256 + wid*64)*8);
  }
  __syncthreads();
  s16x8 qf[2][8];
  #pragma unroll
  for (int qg = 0; qg < 2; ++qg)
    #pragma unroll
    for (int kk = 0; kk < 8; ++kk){
      int row = wid*32 + qg*16 + lc;
      int off = kk*64 + lg*16;
      qf[qg][kk] = *(const s16x8*)((const char*)S.buf + row*512 + (off ^ ((row & 7) << 4)));
    }
  __syncthreads();

  // ones/zero tail rows for both V buffers; stage tile 0
  if (tid < 512){
    us v = (tid < 32) ? (us)0x3F80 : (us)0;
    S.buf[16384 + 8192 + tid] = v;
    S.buf[25088 + 8192 + tid] = v;
  }
  stage_tile(S, 0, Xb, XTb, 0, N, tid);
  __syncthreads();

  f32x4 o[2][16];
  #pragma unroll
  for (int qg = 0; qg < 2; ++qg)
    #pragma unroll
    for (int dcc = 0; dcc < 16; ++dcc) o[qg][dcc] = (f32x4){0.f,0.f,0.f,0.f};
  f32x4 ls[2] = {(f32x4){0.f,0.f,0.f,0.f}, (f32x4){0.f,0.f,0.f,0.f}};

  us* pw = S.ps + wid*32*40;
  const int nt = N/32;
  int cur = 0;

  for (int t = 0; t < nt; ++t){
    if (t + 1 < nt) stage_tile(S, cur^1, Xb, XTb, (t+1)*32, N, tid);

    const us* KS = S.buf + cur*8192;
    const us* VS = S.buf + 16384 + cur*8704;

    // S = Q K^T
    f32x4 s[2][2];
    #pragma unroll
    for (int qg = 0; qg < 2; ++qg)
      #pragma unroll
      for (int kc = 0; kc < 2; ++kc) s[qg][kc] = (f32x4){0.f,0.f,0.f,0.f};
    #pragma unroll
    for (int kk = 0; kk < 8; ++kk){
      #pragma unroll
      for (int kc = 0; kc < 2; ++kc){
        int row = kc*16 + lc;
        int off = kk*64 + lg*16;
        s16x8 kb = *(const s16x8*)((const char*)KS + row*512 + (off ^ ((row & 7) << 4)));
        s[0][kc] = mfma16(qf[0][kk], kb, s[0][kc]);
        s[1][kc] = mfma16(qf[1][kk], kb, s[1][kc]);
      }
    }

    // P = exp(scale*S) -> bf16 scratch (row sums via ones-MFMA below)
    #pragma unroll
    for (int qg = 0; qg < 2; ++qg){
      #pragma unroll
      for (int r = 0; r < 4; ++r){
        float p0 = __expf(s[qg][0][r] * scale);
        float p1 = __expf(s[qg][1][r] * scale);
        int prow = qg*16 + lg*4 + r;
        pw[prow*40 + lc]      = f2bf(p0);
        pw[prow*40 + 16 + lc] = f2bf(p1);
      }
    }

    s16x8 pa[2];
    #pragma unroll
    for (int qg = 0; qg < 2; ++qg)
      pa[qg] = *(const s16x8*)(pw + (qg*16 + lc)*40 + lg*8);

    // O += P V ; row-sums via ones column (vs rows 256..271)
    #pragma unroll
    for (int dcc = 0; dcc < 16; ++dcc){
      s16x8 vf = *(const s16x8*)(VS + (dcc*16 + lc)*32 + lg*8);
      o[0][dcc] = mfma16(pa[0], vf, o[0][dcc]);
      o[1][dcc] = mfma16(pa[1], vf, o[1][dcc]);
    }
    {
      s16x8 vf1 = *(const s16x8*)(VS + (256 + lc)*32 + lg*8);
      ls[0] = mfma16(pa[0], vf1, ls[0]);
      ls[1] = mfma16(pa[1], vf1, ls[1]);
    }

    __syncthreads();
    cur ^= 1;
  }

  // epilogue: normalize (lsum lives in lanes lc==0; broadcast within lg group)
  #pragma unroll
  for (int qg = 0; qg < 2; ++qg){
    #pragma unroll
    for (int r = 0; r < 4; ++r){
      float lv = __shfl(ls[qg][r], lane & 48, 64);
      float inv = 1.f / lv;
      int grow = q0 + wid*32 + qg*16 + lg*4 + r;
      if (grow < N){
        #pragma unroll
        for (int dcc = 0; dcc < 16; ++dcc){
          Outb[(size_t)grow*256 + dcc*16 + lc] = f2bf(o[qg][dcc][r] * inv);
        }
      }
    }
  }
}

template<int N>
__global__ __launch_bounds__(256) void visit_kernel(
    const us* Xg, const us* XgT, us* Out, float scale)
{
  __shared__ VisitLds S;
  const int b = blockIdx.y;
  visit_body<N>(S, Xg + (size_t)b*N*256, XgT + (size_t)b*256*N,
                Out + (size_t)b*N*256, scale, blockIdx.x*128);
}

__global__ __launch_bounds__(256) void visit_fused(
    const us* Xm, const us* XTm, us* Am,
    const us* Xd, const us* XTd, us* Ad,
    const us* Xp, const us* XTp, us* Ap, float scale)
{
  __shared__ VisitLds S;
  // XCD-locality remap: physical p -> XCD p%8; give each XCD a contiguous
  // logical range so blocks sharing a batch's K/V hit the same L2.
  int p = blockIdx.x;
  int l = (p & 7)*92 + (p >> 3);
  if (l < 256){
    int b = l >> 3, q0 = (l & 7)*128;
    visit_body<960>(S, Xm + (size_t)b*960*256, XTm + (size_t)b*256*960,
                    Am + (size_t)b*960*256, scale, q0);
  } else if (l < 576){
    int r = l - 256, b = r/10, q0 = (r - (r/10)*10)*128;
    visit_body<1280>(S, Xd + (size_t)b*1280*256, XTd + (size_t)b*256*1280,
                     Ad + (size_t)b*1280*256, scale, q0);
  } else {
    int r = l - 576, b = r/5, q0 = (r - (r/5)*5)*128;
    visit_body<640>(S, Xp + (size_t)b*640*256, XTp + (size_t)b*256*640,
                    Ap + (size_t)b*640*256, scale, q0);
  }
}

// ---------------- 4) merge attention + med_att, fused per (b,t), MFMA Sr ----------------
__global__ __launch_bounds__(512) void merge_kernel(
    const us* __restrict__ Amed, const us* __restrict__ Adiag,
    const us* __restrict__ Aproc, const float* __restrict__ tf,
    const float* __restrict__ bias, const int* __restrict__ ilen,
    float* __restrict__ out, float scale)
{
  __shared__ us Mb[80*256];  // bf16, 512B rows, XOR-swizzled
  __shared__ float Sr[80*84];
  __shared__ float P[80*84];
  __shared__ float W1[24*76];
  __shared__ float S2[24*76];
  __shared__ float wj[73];
  __shared__ float uk[73];

  const int bt = blockIdx.x, b = bt/40, t = bt - (bt/40)*40;
  const int tid = threadIdx.x, lane = tid & 63, wid = tid >> 6;
  const int lc = lane & 15, lg = lane >> 4;

  for (int c = tid; c < 72*32; c += 512){
    int row = c >> 5, ch = c & 31;
    const us* src;
    if (row < 24)      src = Amed  + ((size_t)b*960  + t*24 + row)*256      + ch*8;
    else if (row < 56) src = Adiag + ((size_t)b*1280 + t*32 + (row-24))*256 + ch*8;
    else               src = Aproc + ((size_t)b*640  + t*16 + (row-56))*256 + ch*8;
    uint4 v = *(const uint4*)src;
    *(uint4*)((char*)Mb + row*512 + ((ch*16) ^ ((row & 7) << 4))) = v;
  }
  if (tid < 256) Mb[72*256 + tid] = f2bf(tf[(size_t)bt*256 + tid]);
  for (int c = tid; c < 7*32; c += 512){
    int row = 73 + (c >> 5), ch = c & 31;
    *(uint4*)((char*)Mb + row*512 + ch*16) = (uint4){0,0,0,0};
  }
  __syncthreads();

  for (int tt = wid; tt < 25; tt += 8){
    int ti = tt/5, tj = tt - (tt/5)*5;
    f32x4 s = (f32x4){0.f,0.f,0.f,0.f};
    #pragma unroll
    for (int kk = 0; kk < 8; ++kk){
      int ra = ti*16 + lc, rb = tj*16 + lc;
      int off = kk*64 + lg*16;
      s16x8 a  = *(const s16x8*)((const char*)Mb + ra*512 + (off ^ ((ra & 7) << 4)));
      s16x8 bb = *(const s16x8*)((const char*)Mb + rb*512 + (off ^ ((rb & 7) << 4)));
      s = mfma16(a, bb, s);
    }
    #pragma unroll
    for (int r = 0; r < 4; ++r)
      Sr[(ti*16 + lg*4 + r)*84 + tj*16 + lc] = s[r];
  }
  __syncthreads();

  for (int r = wid; r < 73; r += 8){
    float e0 = __expf(scale * Sr[r*84 + lane]);
    float e1 = (lane < 9) ? __expf(scale * Sr[r*84 + 64 + lane]) : 0.f;
    float ss = e0 + e1;
    #pragma unroll
    for (int m = 1; m < 64; m <<= 1) ss += __shfl_xor(ss, m, 64);
    float inv = 1.f/ss;
    P[r*84 + lane] = e0 * inv;
    if (lane < 12) P[r*84 + 64 + lane] = (lane < 9) ? e1*inv : 0.f;
  }
  __syncthreads();

  if (tid < 456){
    int i = tid/19, mq = tid - (tid/19)*19;
    f32x4 acc = (f32x4){0.f,0.f,0.f,0.f};
    for (int k = 0; k < 73; ++k){
      float p = P[i*84 + k];
      f32x4 s4 = *(const f32x4*)&Sr[k*84 + mq*4];
      acc.x += p*s4.x; acc.y += p*s4.y; acc.z += p*s4.z; acc.w += p*s4.w;
    }
    *(f32x4*)&W1[i*76 + mq*4] = acc;
  }
  __syncthreads();

  for (int e = tid; e < 24*73; e += 512){
    int i = e/73, j = e - (e/73)*73;
    float acc = 0.f;
    #pragma unroll
    for (int mq = 0; mq < 19; ++mq)
      acc += dot4(*(const f32x4*)&W1[i*76 + mq*4], *(const f32x4*)&P[j*84 + mq*4]);
    S2[i*76 + j] = acc;
  }
  __syncthreads();

  for (int r = wid; r < 24; r += 8){
    float e0 = __expf(S2[r*76 + lane]);
    float e1 = (lane < 9) ? __expf(S2[r*76 + 64 + lane]) : 0.f;
    float ss = e0 + e1;
    #pragma unroll
    for (int m = 1; m < 64; m <<= 1) ss += __shfl_xor(ss, m, 64);
    float inv = 1.f/ss;
    S2[r*76 + lane] = e0*inv;
    if (lane < 12) S2[r*76 + 64 + lane] = (lane < 9) ? e1*inv : 0.f;
  }
  __syncthreads();

  if (tid < 73){
    float a = 0.f;
    #pragma unroll
    for (int i = 0; i < 24; ++i) a += S2[i*76 + tid];
    wj[tid] = a;
  }
  __syncthreads();
  if (tid < 73){
    float a = 0.f;
    for (int j = 0; j < 73; ++j) a += wj[j]*P[j*84 + tid];
    uk[tid] = a;
  }
  __syncthreads();

  if (tid < 256){
    float acc = bias[tid];
    if (t < ilen[b]){
      float ex = (float)(2*(tid>>1)) * (1.0f/256.0f);
      float dv = powf(10000.f, ex);
      float ang = (float)t / dv;
      acc += (tid & 1) ? cosf(ang) : sinf(ang);
    }
    for (int k = 0; k < 73; ++k){
      us m = *(const us*)((const char*)Mb + k*512 + ((tid*2) ^ ((k & 7) << 4)));
      acc += uk[k] * bf2f(m);
    }
    out[(size_t)bt*256 + tid] = acc;
  }
}

// ---------------- launch ----------------
extern "C" void kernel_launch(void* const* d_in, const int* in_sizes, int n_in,
                              void* d_out, int out_size, void* d_ws, size_t ws_size,
                              hipStream_t stream)
{
  (void)in_sizes; (void)n_in; (void)out_size;

  const int*   med_codes = (const int*)  d_in[0];
  const int*   diag_codes= (const int*)  d_in[1];
  const int*   proc_codes= (const int*)  d_in[2];
  const float* med_mask  = (const float*)d_in[3];
  const float* diag_mask = (const float*)d_in[4];
  const float* proc_mask = (const float*)d_in[5];
  const float* seq_time  = (const float*)d_in[6];
  const int*   input_len = (const int*)  d_in[7];
  const float* emb_med   = (const float*)d_in[8];
  const float* emb_diag  = (const float*)d_in[9];
  const float* emb_proc  = (const float*)d_in[10];
  const float* bias_med  = (const float*)d_in[11];
  const float* W_sel     = (const float*)d_in[12];
  const float* b_sel     = (const float*)d_in[13];
  const float* W_time    = (const float*)d_in[14];
  const float* b_time    = (const float*)d_in[15];
  const float* Wg_med    = (const float*)d_in[16];
  const float* bg_med    = (const float*)d_in[17];
  const float* Wg_diag   = (const float*)d_in[18];
  const float* bg_diag   = (const float*)d_in[19];
  const float* Wg_proc   = (const float*)d_in[20];
  const float* bg_proc   = (const float*)d_in[21];

  const float scale = (float)(1.0 / sqrt(256.0 + 1e-7));

  char* ws = (char*)d_ws;
  const size_t sz_tf = (size_t)1280*256*4;
  const size_t szA_m = (size_t)32*960*256*2;
  const size_t szA_d = (size_t)32*1280*256*2;
  const size_t szA_p = (size_t)32*640*256*2;

  size_t off = 0;
  float* tf   = (float*)(ws + off); off += sz_tf;
  us* Am      = (us*)(ws + off);    off += szA_m;
  us* Ad      = (us*)(ws + off);    off += szA_d;
  us* Ap      = (us*)(ws + off);    off += szA_p;

  const size_t fused_need = off + 2*(szA_m + szA_d + szA_p);
  tf_kernel<<<1280, 256, 0, stream>>>(seq_time, W_sel, b_sel, W_time, b_time, tf);

  if (ws_size >= fused_need){
    us* Xm  = (us*)(ws + off); off += szA_m;
    us* XTm = (us*)(ws + off); off += szA_m;
    us* Xd  = (us*)(ws + off); off += szA_d;
    us* XTd = (us*)(ws + off); off += szA_d;
    us* Xp  = (us*)(ws + off); off += szA_p;
    us* XTp = (us*)(ws + off); off += szA_p;

    gate_fused<<<3840, 256, 0, stream>>>(
        med_codes, diag_codes, proc_codes, med_mask, diag_mask, proc_mask,
        emb_med, emb_diag, emb_proc, tf,
        Wg_med, bg_med, Wg_diag, bg_diag, Wg_proc, bg_proc,
        Xm, XTm, Xd, XTd, Xp, XTp, scale);

    visit_fused<<<736, 256, 0, stream>>>(Xm, XTm, Am, Xd, XTd, Ad, Xp, XTp, Ap, scale);
  } else {
    us* Xg  = (us*)(ws + off);
    us* XgT = (us*)(ws + off + szA_d);

    gate_kernel<24,960><<<1280, 256, 0, stream>>>(med_codes, med_mask, emb_med, tf, Wg_med, bg_med, Xg, XgT, scale);
    visit_kernel<960><<<dim3(8,32), 256, 0, stream>>>(Xg, XgT, Am, scale);

    gate_kernel<32,1280><<<1280, 256, 0, stream>>>(diag_codes, diag_mask, emb_diag, tf, Wg_diag, bg_diag, Xg, XgT, scale);
    visit_kernel<1280><<<dim3(10,32), 256, 0, stream>>>(Xg, XgT, Ad, scale);

    gate_kernel<16,640><<<1280, 256, 0, stream>>>(proc_codes, proc_mask, emb_proc, tf, Wg_proc, bg_proc, Xg, XgT, scale);
    visit_kernel<640><<<dim3(5,32), 256, 0, stream>>>(Xg, XgT, Ap, scale);
  }

  merge_kernel<<<1280, 512, 0, stream>>>(Am, Ad, Ap, tf, bias_med, input_len, (float*)d_out, scale);
}

// Round 4
// 354.177 us; speedup vs baseline: 3.6524x; 1.2497x over previous
//
#include <hip/hip_runtime.h>
#include <hip/hip_bf16.h>
#include <math.h>

// ---------------- types / helpers ----------------
typedef float f32x4 __attribute__((ext_vector_type(4)));
typedef short s16x8 __attribute__((ext_vector_type(8)));
typedef unsigned short us;

__device__ __forceinline__ float bf2f(us u){
  union { unsigned int i; float f; } v; v.i = ((unsigned int)u) << 16; return v.f;
}
__device__ __forceinline__ us f2bf(float f){
  union { float f; unsigned int i; } v; v.f = f;
  unsigned int r = v.i + 0x7FFFu + ((v.i >> 16) & 1u);
  return (us)(r >> 16);
}
__device__ __forceinline__ float dot4(f32x4 a, f32x4 b){
  return a.x*b.x + a.y*b.y + a.z*b.z + a.w*b.w;
}
__device__ __forceinline__ f32x4 mfma16(s16x8 a, s16x8 b, f32x4 c){
  return __builtin_amdgcn_mfma_f32_16x16x32_bf16(a, b, c, 0, 0, 0);
}
// async global->LDS, 16B per lane; dst must be wave-uniform base (HW adds lane*16)
__device__ __forceinline__ void gld16(const us* src, us* dst){
  __builtin_amdgcn_global_load_lds(
      (const __attribute__((address_space(1))) unsigned int*)src,
      (__attribute__((address_space(3))) unsigned int*)dst, 16, 0, 0);
}

#define VM_WAIT8()  asm volatile("s_waitcnt vmcnt(8)" ::: "memory")
#define VM_WAIT0()  asm volatile("s_waitcnt vmcnt(0)" ::: "memory")
#define LGKM_WAIT0() asm volatile("s_waitcnt lgkmcnt(0)" ::: "memory")
#define PRO_WAIT()  asm volatile("s_waitcnt vmcnt(8) lgkmcnt(0)" ::: "memory")
#define BAR()       __builtin_amdgcn_s_barrier()

// ---------------- 1) time_feature ----------------
__global__ __launch_bounds__(256) void tf_kernel(
    const float* __restrict__ seq, const float* __restrict__ Wsel,
    const float* __restrict__ bsel, const float* __restrict__ Wtime,
    const float* __restrict__ btime, float* __restrict__ tf)
{
  const int bt = blockIdx.x, tid = threadIdx.x;
  __shared__ float w1[64];
  float s = seq[bt];
  if (tid < 64){ float h = s*Wsel[tid] + bsel[tid]; w1[tid] = 1.0f - tanhf(h*h); }
  __syncthreads();
  const float* wrow = Wtime + (size_t)tid*64;
  float acc = btime[tid];
  #pragma unroll 8
  for (int j = 0; j < 64; ++j) acc += w1[j]*wrow[j];
  tf[(size_t)bt*256 + tid] = acc;
}

// ---------------- 2) embed + gate ----------------
struct GateLds {
  float E[32*260];
  float sc[64];
  float tfs[256];
  float gs[256];
};

template<int L, int N>
__device__ __forceinline__ void gate_body(GateLds& S,
    const int* __restrict__ codes, const float* __restrict__ mask,
    const float* __restrict__ emb, const float* __restrict__ tf,
    const float* __restrict__ Wg, const float* __restrict__ bg,
    us* __restrict__ Xg, us* __restrict__ XgT, float scale, int bt)
{
  const int b = bt/40, t = bt - (bt/40)*40;
  const int tid = threadIdx.x, lane = tid & 63, wid = tid >> 6;

  S.tfs[tid] = tf[(size_t)bt*256 + tid];
  #pragma unroll
  for (int l = 0; l < L; ++l){
    int code = codes[bt*L + l];
    float m = mask[bt*L + l];
    S.E[l*260 + tid] = emb[(size_t)code*256 + tid] * m;
  }
  __syncthreads();

  constexpr int RPW = (L + 3)/4;
  #pragma unroll
  for (int rr = 0; rr < RPW; ++rr){
    int l = wid*RPW + rr;
    if (l < L){
      f32x4 e4 = *(const f32x4*)&S.E[l*260 + lane*4];
      f32x4 t4 = *(const f32x4*)&S.tfs[lane*4];
      float p = dot4(e4, t4);
      #pragma unroll
      for (int m = 1; m < 64; m <<= 1) p += __shfl_xor(p, m, 64);
      if (lane == 0) S.sc[l] = p * scale;
    }
  }
  __syncthreads();
  if (wid == 0){
    float p = (lane < L) ? __expf(S.sc[lane]) : 0.f;
    float ss = p;
    #pragma unroll
    for (int m = 1; m < 64; m <<= 1) ss += __shfl_xor(ss, m, 64);
    if (lane < L) S.sc[lane] = p / ss;
  }
  __syncthreads();

  float g = 0.f;
  #pragma unroll
  for (int l = 0; l < L; ++l) g += S.sc[l]*S.E[l*260 + tid];
  S.gs[tid] = g;
  __syncthreads();

  const float* wrow = Wg + (size_t)tid*256;
  float a2 = bg[tid];
  #pragma unroll
  for (int e = 0; e < 256; e += 4){
    f32x4 w4 = *(const f32x4*)&wrow[e];
    f32x4 g4 = *(const f32x4*)&S.gs[e];
    a2 += dot4(w4, g4);
  }
  float g2 = 1.f/(1.f + __expf(-a2));

  us tbuf[L];
  #pragma unroll
  for (int l = 0; l < L; ++l){
    us h = f2bf(g2 * S.E[l*260 + tid]);
    Xg[((size_t)b*N + t*L + l)*256 + tid] = h;
    tbuf[l] = h;
  }
  size_t tb = ((size_t)b*256 + tid)*N + (size_t)t*L;
  #pragma unroll
  for (int l = 0; l < L; l += 8){
    uint4 v;
    v.x = (unsigned)tbuf[l+0] | ((unsigned)tbuf[l+1] << 16);
    v.y = (unsigned)tbuf[l+2] | ((unsigned)tbuf[l+3] << 16);
    v.z = (unsigned)tbuf[l+4] | ((unsigned)tbuf[l+5] << 16);
    v.w = (unsigned)tbuf[l+6] | ((unsigned)tbuf[l+7] << 16);
    *(uint4*)&XgT[tb + l] = v;
  }
}

template<int L, int N>
__global__ __launch_bounds__(256) void gate_kernel(
    const int* codes, const float* mask, const float* emb, const float* tf,
    const float* Wg, const float* bg, us* Xg, us* XgT, float scale)
{
  __shared__ GateLds S;
  gate_body<L,N>(S, codes, mask, emb, tf, Wg, bg, Xg, XgT, scale, blockIdx.x);
}

__global__ __launch_bounds__(256) void gate_fused(
    const int* mc, const int* dc, const int* pc,
    const float* mm, const float* dm, const float* pm,
    const float* em, const float* ed, const float* ep,
    const float* tf,
    const float* Wgm, const float* bgm, const float* Wgd, const float* bgd,
    const float* Wgp, const float* bgp,
    us* Xm, us* XTm, us* Xd, us* XTd, us* Xp, us* XTp, float scale)
{
  __shared__ GateLds S;
  int bid = blockIdx.x;
  if (bid < 1280)      gate_body<24,960 >(S, mc, mm, em, tf, Wgm, bgm, Xm, XTm, scale, bid);
  else if (bid < 2560) gate_body<32,1280>(S, dc, dm, ed, tf, Wgd, bgd, Xd, XTd, scale, bid-1280);
  else                 gate_body<16,640 >(S, pc, pm, ep, tf, Wgp, bgp, Xp, XTp, scale, bid-2560);
}

// ---------------- 3) visit self-attention (flash, bf16 MFMA, counted-vmcnt dbuf) ----------------
// LDS map (shorts): KS0 [0,8192) KS1 [8192,16384) VS0 [16384,25088) VS1 [25088,33792)
// VSx rows 0..255 = V^T [d][k] tile (linear, staged); rows 256..271: row256=ones, rest 0.
struct VisitLds {
  us buf[33792];
  us ps[4*32*40];   // per-wave P scratch [32][40]
};

__device__ __forceinline__ void stage_tile(VisitLds& S, int cur,
    const us* __restrict__ Xb, const us* __restrict__ XTb, int k0, int N_, int tid)
{
  const int wid = tid >> 6;
  us* KS = S.buf + cur*8192;
  us* VS = S.buf + 16384 + cur*8704;
  #pragma unroll
  for (int i = 0; i < 4; ++i){
    int c = tid + i*256;
    int row = c >> 5, ch = c & 31;
    gld16(Xb + (size_t)(k0 + row)*256 + (((ch*16) ^ ((row & 7) << 4)) >> 1),
          KS + (i*256 + wid*64)*8);
    int d = c >> 2, kslot = c & 3;
    gld16(XTb + (size_t)d*N_ + k0 + kslot*8,
          VS + (i*256 + wid*64)*8);
  }
}

template<int N>
__device__ __forceinline__ void visit_body(VisitLds& S,
    const us* __restrict__ Xb, const us* __restrict__ XTb,
    us* __restrict__ Outb, float scale, int q0)
{
  const int tid = threadIdx.x, lane = tid & 63, wid = tid >> 6;
  const int lc = lane & 15, lg = lane >> 4;

  // ---- direct-register Q loads (no LDS round-trip) ----
  s16x8 qf[2][8];
  #pragma unroll
  for (int qg = 0; qg < 2; ++qg)
    #pragma unroll
    for (int kk = 0; kk < 8; ++kk){
      int gr = q0 + wid*32 + qg*16 + lc;
      gr = gr < N ? gr : N-1;
      qf[qg][kk] = *(const s16x8*)(Xb + (size_t)gr*256 + kk*32 + lg*8);
    }

  // ones/zero tail rows for both V buffers
  for (int i = tid; i < 512; i += 256){
    us v = (i < 32) ? (us)0x3F80 : (us)0;
    S.buf[16384 + 8192 + i] = v;
    S.buf[25088 + 8192 + i] = v;
  }

  // prologue: prefetch tiles 0 and 1
  stage_tile(S, 0, Xb, XTb, 0, N, tid);
  stage_tile(S, 1, Xb, XTb, 32, N, tid);
  PRO_WAIT();          // tile 0 landed (and ones rows visible)
  BAR();

  f32x4 o[2][16];
  #pragma unroll
  for (int qg = 0; qg < 2; ++qg)
    #pragma unroll
    for (int dcc = 0; dcc < 16; ++dcc) o[qg][dcc] = (f32x4){0.f,0.f,0.f,0.f};
  f32x4 ls[2] = {(f32x4){0.f,0.f,0.f,0.f}, (f32x4){0.f,0.f,0.f,0.f}};

  us* pw = S.ps + wid*32*40;
  const int nt = N/32;

  auto compute_tile = [&](int c){
    const us* KS = S.buf + c*8192;
    const us* VS = S.buf + 16384 + c*8704;

    f32x4 s[2][2];
    #pragma unroll
    for (int qg = 0; qg < 2; ++qg)
      #pragma unroll
      for (int kc = 0; kc < 2; ++kc) s[qg][kc] = (f32x4){0.f,0.f,0.f,0.f};

    __builtin_amdgcn_s_setprio(1);
    #pragma unroll
    for (int kk = 0; kk < 8; ++kk){
      #pragma unroll
      for (int kc = 0; kc < 2; ++kc){
        int row = kc*16 + lc;
        int off = kk*64 + lg*16;
        s16x8 kb = *(const s16x8*)((const char*)KS + row*512 + (off ^ ((row & 7) << 4)));
        s[0][kc] = mfma16(qf[0][kk], kb, s[0][kc]);
        s[1][kc] = mfma16(qf[1][kk], kb, s[1][kc]);
      }
    }
    __builtin_amdgcn_s_setprio(0);

    #pragma unroll
    for (int qg = 0; qg < 2; ++qg){
      #pragma unroll
      for (int r = 0; r < 4; ++r){
        float p0 = __expf(s[qg][0][r] * scale);
        float p1 = __expf(s[qg][1][r] * scale);
        int prow = qg*16 + lg*4 + r;
        pw[prow*40 + lc]      = f2bf(p0);
        pw[prow*40 + 16 + lc] = f2bf(p1);
      }
    }

    s16x8 pa[2];
    #pragma unroll
    for (int qg = 0; qg < 2; ++qg)
      pa[qg] = *(const s16x8*)(pw + (qg*16 + lc)*40 + lg*8);

    __builtin_amdgcn_s_setprio(1);
    #pragma unroll
    for (int dcc = 0; dcc < 16; ++dcc){
      s16x8 vf = *(const s16x8*)(VS + (dcc*16 + lc)*32 + lg*8);
      o[0][dcc] = mfma16(pa[0], vf, o[0][dcc]);
      o[1][dcc] = mfma16(pa[1], vf, o[1][dcc]);
    }
    {
      s16x8 vf1 = *(const s16x8*)(VS + (256 + lc)*32 + lg*8);
      ls[0] = mfma16(pa[0], vf1, ls[0]);
      ls[1] = mfma16(pa[1], vf1, ls[1]);
    }
    __builtin_amdgcn_s_setprio(0);
  };

  for (int t = 0; t < nt; ++t){
    compute_tile(t & 1);
    if (t == nt-1) break;
    LGKM_WAIT0();                  // all reads of buf[t&1] retired
    BAR();                         // every wave done reading -> safe to overwrite
    if (t + 2 < nt){
      stage_tile(S, t & 1, Xb, XTb, (t+2)*32, N, tid);
      VM_WAIT8();                  // tile t+1 fully landed (only t+2's 8 may fly)
    } else {
      VM_WAIT0();                  // no new issue: drain to guarantee t+1
    }
    BAR();                         // tile t+1 visible to all waves
  }

  // epilogue: normalize (lsum valid in lc==0 lanes; broadcast within lg group)
  #pragma unroll
  for (int qg = 0; qg < 2; ++qg){
    #pragma unroll
    for (int r = 0; r < 4; ++r){
      float lv = __shfl(ls[qg][r], lane & 48, 64);
      float inv = 1.f / lv;
      int grow = q0 + wid*32 + qg*16 + lg*4 + r;
      if (grow < N){
        #pragma unroll
        for (int dcc = 0; dcc < 16; ++dcc){
          Outb[(size_t)grow*256 + dcc*16 + lc] = f2bf(o[qg][dcc][r] * inv);
        }
      }
    }
  }
}

template<int N>
__global__ __launch_bounds__(256, 2) void visit_kernel(
    const us* Xg, const us* XgT, us* Out, float scale)
{
  __shared__ VisitLds S;
  const int b = blockIdx.y;
  visit_body<N>(S, Xg + (size_t)b*N*256, XgT + (size_t)b*256*N,
                Out + (size_t)b*N*256, scale, blockIdx.x*128);
}

__global__ __launch_bounds__(256, 2) void visit_fused(
    const us* Xm, const us* XTm, us* Am,
    const us* Xd, const us* XTd, us* Ad,
    const us* Xp, const us* XTp, us* Ap, float scale)
{
  __shared__ VisitLds S;
  // XCD-locality remap: 736 = 8*92, p%8 = XCD -> contiguous logical chunk per XCD
  int p = blockIdx.x;
  int l = (p & 7)*92 + (p >> 3);
  if (l < 256){
    int b = l >> 3, q0 = (l & 7)*128;
    visit_body<960>(S, Xm + (size_t)b*960*256, XTm + (size_t)b*256*960,
                    Am + (size_t)b*960*256, scale, q0);
  } else if (l < 576){
    int r = l - 256, b = r/10, q0 = (r - (r/10)*10)*128;
    visit_body<1280>(S, Xd + (size_t)b*1280*256, XTd + (size_t)b*256*1280,
                     Ad + (size_t)b*1280*256, scale, q0);
  } else {
    int r = l - 576, b = r/5, q0 = (r - (r/5)*5)*128;
    visit_body<640>(S, Xp + (size_t)b*640*256, XTp + (size_t)b*256*640,
                    Ap + (size_t)b*640*256, scale, q0);
  }
}

// ---------------- 4) merge attention + med_att, fused per (b,t), all-MFMA GEMMs ----------------
// out = sum_k u[k]*M[k] + bias + pos, u = w^T P, w_j = sum_{i<24} P2[i][j],
// P2 = softmax(W1 P^T rows<24), W1 = (P Sr)[0:24], P = softmax(scale*Sr), Sr = M M^T (symmetric)
__global__ __launch_bounds__(512, 2) void merge_kernel(
    const us* __restrict__ Amed, const us* __restrict__ Adiag,
    const us* __restrict__ Aproc, const float* __restrict__ tf,
    const float* __restrict__ bias, const int* __restrict__ ilen,
    float* __restrict__ out, float scale)
{
  __shared__ alignas(16) us Mb[80*256];   // 40960 B, 512B rows, XOR-swizzled
  __shared__ alignas(16) us SrB[80*96];   // 15360 B, bf16 Sr (also aliased by S2f later)
  __shared__ alignas(16) us Pb[80*96];    // 15360 B, bf16 P
  __shared__ alignas(16) us W1B[32*96];   //  6144 B, bf16 W1
  __shared__ float wj[73];
  __shared__ float uk[73];
  float* S2f = (float*)SrB;               // 32*84*4 = 10752 B, aliases SrB (dead by then)

  const int bt = blockIdx.x, b = bt/40, t = bt - (bt/40)*40;
  const int tid = threadIdx.x, lane = tid & 63, wid = tid >> 6;
  const int lc = lane & 15, lg = lane >> 4;

  // ---- phase 1: stage M (rows 0..71 bf16, row 72 = tf, rows 73..79 zero) ----
  for (int c = tid; c < 72*32; c += 512){
    int row = c >> 5, ch = c & 31;
    const us* src;
    if (row < 24)      src = Amed  + ((size_t)b*960  + t*24 + row)*256      + ch*8;
    else if (row < 56) src = Adiag + ((size_t)b*1280 + t*32 + (row-24))*256 + ch*8;
    else               src = Aproc + ((size_t)b*640  + t*16 + (row-56))*256 + ch*8;
    uint4 v = *(const uint4*)src;
    *(uint4*)((char*)Mb + row*512 + ((ch*16) ^ ((row & 7) << 4))) = v;
  }
  if (tid < 256) Mb[72*256 + tid] = f2bf(tf[(size_t)bt*256 + tid]);
  for (int c = tid; c < 7*32; c += 512){
    int row = 73 + (c >> 5), ch = c & 31;
    *(uint4*)((char*)Mb + row*512 + ch*16) = (uint4){0,0,0,0};
  }
  __syncthreads();

  // ---- phase 2: Sr = M M^T via MFMA (5x5 tiles, K=256), write bf16 ----
  for (int tt = wid; tt < 25; tt += 8){
    int ti = tt/5, tj = tt - (tt/5)*5;
    f32x4 s = (f32x4){0.f,0.f,0.f,0.f};
    #pragma unroll
    for (int kk = 0; kk < 8; ++kk){
      int ra = ti*16 + lc, rb = tj*16 + lc;
      int off = kk*64 + lg*16;
      s16x8 a  = *(const s16x8*)((const char*)Mb + ra*512 + (off ^ ((ra & 7) << 4)));
      s16x8 bb = *(const s16x8*)((const char*)Mb + rb*512 + (off ^ ((rb & 7) << 4)));
      s = mfma16(a, bb, s);
    }
    #pragma unroll
    for (int r = 0; r < 4; ++r)
      SrB[(ti*16 + lg*4 + r)*96 + tj*16 + lc] = f2bf(s[r]);
  }
  __syncthreads();

  // ---- phase 3: P = row-softmax(scale*Sr) cols<73 -> bf16; pads zeroed ----
  for (int c = tid; c < 80*16; c += 512){                // SrB cols 80..95 := 0
    int r = c >> 4;
    SrB[r*96 + 80 + (c & 15)] = 0;
  }
  for (int r = wid; r < 73; r += 8){
    float e0 = __expf(scale * bf2f(SrB[r*96 + lane]));
    float e1 = (lane < 9) ? __expf(scale * bf2f(SrB[r*96 + 64 + lane])) : 0.f;
    float ss = e0 + e1;
    #pragma unroll
    for (int m = 1; m < 64; m <<= 1) ss += __shfl_xor(ss, m, 64);
    float inv = 1.f/ss;
    Pb[r*96 + lane] = f2bf(e0 * inv);
    if (lane < 32) Pb[r*96 + 64 + lane] = (lane < 9) ? f2bf(e1*inv) : (us)0;
  }
  for (int c = tid; c < 7*96; c += 512){                 // Pb rows 73..79 := 0
    Pb[73*96 + c] = 0;
  }
  __syncthreads();

  // ---- phase 4: W1 = P(0:32) * Sr via MFMA (Sr symmetric), K=96, write bf16 ----
  for (int tt = wid; tt < 10; tt += 8){
    int ri = tt/5, cj = tt - (tt/5)*5;
    f32x4 s = (f32x4){0.f,0.f,0.f,0.f};
    #pragma unroll
    for (int kk = 0; kk < 3; ++kk){
      s16x8 a  = *(const s16x8*)(Pb  + (ri*16 + lc)*96 + kk*32 + lg*8);
      s16x8 bb = *(const s16x8*)(SrB + (cj*16 + lc)*96 + kk*32 + lg*8);
      s = mfma16(a, bb, s);
    }
    #pragma unroll
    for (int r = 0; r < 4; ++r)
      W1B[(ri*16 + lg*4 + r)*96 + cj*16 + lc] = f2bf(s[r]);
  }
  if (tid < 512){                                        // W1B cols 80..95 := 0
    W1B[(tid >> 4)*96 + 80 + (tid & 15)] = 0;
  }
  __syncthreads();

  // ---- phase 5: S2 = W1 * P^T via MFMA, K=96, write f32 into S2f (aliases SrB) ----
  for (int tt = wid; tt < 10; tt += 8){
    int ri = tt/5, cj = tt - (tt/5)*5;
    f32x4 s = (f32x4){0.f,0.f,0.f,0.f};
    #pragma unroll
    for (int kk = 0; kk < 3; ++kk){
      s16x8 a  = *(const s16x8*)(W1B + (ri*16 + lc)*96 + kk*32 + lg*8);
      s16x8 bb = *(const s16x8*)(Pb  + (cj*16 + lc)*96 + kk*32 + lg*8);
      s = mfma16(a, bb, s);
    }
    #pragma unroll
    for (int r = 0; r < 4; ++r)
      S2f[(ri*16 + lg*4 + r)*84 + cj*16 + lc] = s[r];
  }
  __syncthreads();

  // ---- phase 6: P2 = row-softmax(S2) rows<24, in place ----
  for (int r = wid; r < 24; r += 8){
    float e0 = __expf(S2f[r*84 + lane]);
    float e1 = (lane < 9) ? __expf(S2f[r*84 + 64 + lane]) : 0.f;
    float ss = e0 + e1;
    #pragma unroll
    for (int m = 1; m < 64; m <<= 1) ss += __shfl_xor(ss, m, 64);
    float inv = 1.f/ss;
    S2f[r*84 + lane] = e0*inv;
    if (lane < 12) S2f[r*84 + 64 + lane] = (lane < 9) ? e1*inv : 0.f;
  }
  __syncthreads();

  // ---- phase 7: wj, then uk ----
  if (tid < 73){
    float a = 0.f;
    #pragma unroll
    for (int i = 0; i < 24; ++i) a += S2f[i*84 + tid];
    wj[tid] = a;
  }
  __syncthreads();
  if (tid < 73){
    float a = 0.f;
    for (int j = 0; j < 73; ++j) a += wj[j] * bf2f(Pb[j*96 + tid]);
    uk[tid] = a;
  }
  __syncthreads();

  // ---- phase 8: out = bias + pos + sum_k uk[k]*M[k] ----
  if (tid < 256){
    float acc = bias[tid];
    if (t < ilen[b]){
      float ex = (float)(2*(tid>>1)) * (1.0f/256.0f);
      float dv = powf(10000.f, ex);
      float ang = (float)t / dv;
      acc += (tid & 1) ? cosf(ang) : sinf(ang);
    }
    for (int k = 0; k < 73; ++k){
      us m = *(const us*)((const char*)Mb + k*512 + ((tid*2) ^ ((k & 7) << 4)));
      acc += uk[k] * bf2f(m);
    }
    out[(size_t)bt*256 + tid] = acc;
  }
}

// ---------------- launch ----------------
extern "C" void kernel_launch(void* const* d_in, const int* in_sizes, int n_in,
                              void* d_out, int out_size, void* d_ws, size_t ws_size,
                              hipStream_t stream)
{
  (void)in_sizes; (void)n_in; (void)out_size;

  const int*   med_codes = (const int*)  d_in[0];
  const int*   diag_codes= (const int*)  d_in[1];
  const int*   proc_codes= (const int*)  d_in[2];
  const float* med_mask  = (const float*)d_in[3];
  const float* diag_mask = (const float*)d_in[4];
  const float* proc_mask = (const float*)d_in[5];
  const float* seq_time  = (const float*)d_in[6];
  const int*   input_len = (const int*)  d_in[7];
  const float* emb_med   = (const float*)d_in[8];
  const float* emb_diag  = (const float*)d_in[9];
  const float* emb_proc  = (const float*)d_in[10];
  const float* bias_med  = (const float*)d_in[11];
  const float* W_sel     = (const float*)d_in[12];
  const float* b_sel     = (const float*)d_in[13];
  const float* W_time    = (const float*)d_in[14];
  const float* b_time    = (const float*)d_in[15];
  const float* Wg_med    = (const float*)d_in[16];
  const float* bg_med    = (const float*)d_in[17];
  const float* Wg_diag   = (const float*)d_in[18];
  const float* bg_diag   = (const float*)d_in[19];
  const float* Wg_proc   = (const float*)d_in[20];
  const float* bg_proc   = (const float*)d_in[21];

  const float scale = (float)(1.0 / sqrt(256.0 + 1e-7));

  char* ws = (char*)d_ws;
  const size_t sz_tf = (size_t)1280*256*4;
  const size_t szA_m = (size_t)32*960*256*2;
  const size_t szA_d = (size_t)32*1280*256*2;
  const size_t szA_p = (size_t)32*640*256*2;

  size_t off = 0;
  float* tf   = (float*)(ws + off); off += sz_tf;
  us* Am      = (us*)(ws + off);    off += szA_m;
  us* Ad      = (us*)(ws + off);    off += szA_d;
  us* Ap      = (us*)(ws + off);    off += szA_p;

  const size_t fused_need = off + 2*(szA_m + szA_d + szA_p);
  tf_kernel<<<1280, 256, 0, stream>>>(seq_time, W_sel, b_sel, W_time, b_time, tf);

  if (ws_size >= fused_need){
    us* Xm  = (us*)(ws + off); off += szA_m;
    us* XTm = (us*)(ws + off); off += szA_m;
    us* Xd  = (us*)(ws + off); off += szA_d;
    us* XTd = (us*)(ws + off); off += szA_d;
    us* Xp  = (us*)(ws + off); off += szA_p;
    us* XTp = (us*)(ws + off); off += szA_p;

    gate_fused<<<3840, 256, 0, stream>>>(
        med_codes, diag_codes, proc_codes, med_mask, diag_mask, proc_mask,
        emb_med, emb_diag, emb_proc, tf,
        Wg_med, bg_med, Wg_diag, bg_diag, Wg_proc, bg_proc,
        Xm, XTm, Xd, XTd, Xp, XTp, scale);

    visit_fused<<<736, 256, 0, stream>>>(Xm, XTm, Am, Xd, XTd, Ad, Xp, XTp, Ap, scale);
  } else {
    us* Xg  = (us*)(ws + off);
    us* XgT = (us*)(ws + off + szA_d);

    gate_kernel<24,960><<<1280, 256, 0, stream>>>(med_codes, med_mask, emb_med, tf, Wg_med, bg_med, Xg, XgT, scale);
    visit_kernel<960><<<dim3(8,32), 256, 0, stream>>>(Xg, XgT, Am, scale);

    gate_kernel<32,1280><<<1280, 256, 0, stream>>>(diag_codes, diag_mask, emb_diag, tf, Wg_diag, bg_diag, Xg, XgT, scale);
    visit_kernel<1280><<<dim3(10,32), 256, 0, stream>>>(Xg, XgT, Ad, scale);

    gate_kernel<16,640><<<1280, 256, 0, stream>>>(proc_codes, proc_mask, emb_proc, tf, Wg_proc, bg_proc, Xg, XgT, scale);
    visit_kernel<640><<<dim3(5,32), 256, 0, stream>>>(Xg, XgT, Ap, scale);
  }

  merge_kernel<<<1280, 512, 0, stream>>>(Am, Ad, Ap, tf, bias_med, input_len, (float*)d_out, scale);
}